// Round 19
// baseline (74.580 us; speedup 1.0000x reference)
//
#include <hip/hip_runtime.h>

#define NC 32     // num_capsule
#define DC 16     // dim_capsule
#define INC 144   // input capsules
#define IND 8     // input dim
#define NT 1024   // threads: (b 0..31) x (half 0..1) x (cg 0..15)
#define LG_S 152  // halves per b row of logits

typedef _Float16 h2 __attribute__((ext_vector_type(2)));
typedef _Float16 h4v __attribute__((ext_vector_type(4)));
typedef _Float16 h8 __attribute__((ext_vector_type(8)));
typedef float f4 __attribute__((ext_vector_type(4)));

union H8 { h8 v; h2 p[4]; _Float16 e[8]; };

#if __has_builtin(__builtin_amdgcn_fdot2)
__device__ __forceinline__ float fdot2(h2 a, h2 b, float c) {
    return __builtin_amdgcn_fdot2(a, b, c, false);
}
#else
__device__ __forceinline__ float fdot2(h2 a, h2 b, float c) {
    return c + (float)a[0] * (float)b[0] + (float)a[1] * (float)b[1];
}
#endif

// Convert+TRANSPOSE W: fp32 [b][c][d][i] -> fp16 h8-slots [(b*9+k)*16+d][cg],
// c = cg + 16k. 73728 h8 slots -> grid 288 x 256.
__global__ void convw_kernel(const float* __restrict__ W, _Float16* __restrict__ Wh) {
    int i = blockIdx.x * 256 + threadIdx.x;          // h8 slot 0..73727
    int cg = i & 15, d = (i >> 4) & 15, bk = i >> 8; // bk = b*9+k, 0..287
    int k = bk % 9, b = bk / 9;
    const float* s = W + (((size_t)b * INC + cg + 16 * k) * DC + d) * IND;
    f4 v0 = *reinterpret_cast<const f4*>(s);
    f4 v1 = *reinterpret_cast<const f4*>(s + 4);
    H8 o;
    o.e[0] = (_Float16)v0[0]; o.e[1] = (_Float16)v0[1];
    o.e[2] = (_Float16)v0[2]; o.e[3] = (_Float16)v0[3];
    o.e[4] = (_Float16)v1[0]; o.e[5] = (_Float16)v1[1];
    o.e[6] = (_Float16)v1[2]; o.e[7] = (_Float16)v1[3];
    *reinterpret_cast<h8*>(Wh + (size_t)i * 8) = o.v;
}

#define R8(M)  M(0) M(1) M(2) M(3) M(4) M(5) M(6) M(7)
#define R9(M)  M(0) M(1) M(2) M(3) M(4) M(5) M(6) M(7) M(8)
#define R16(M) M(0) M(1) M(2) M(3) M(4) M(5) M(6) M(7) M(8) M(9) M(10) M(11) M(12) M(13) M(14) M(15)

template <typename WT>
__global__ __launch_bounds__(NT, 4)  // 4 waves/EU -> 128-VGPR budget; demand ~90 fits (no spill)
void caps_kernel(const float* __restrict__ xg, const WT* __restrict__ Wg,
                 float* __restrict__ out) {
    __shared__ __align__(16) _Float16 x_h[INC * IND];  // 2304 B
    __shared__ __align__(16) _Float16 lg[NC * LG_S];   // 9728 B

    const int t = threadIdx.x;
    const int cg = t & 15;        // c-group: owns c = cg + 16k
    const int half = (t >> 4) & 1; // d-half: owns d = half*8 + 0..7
    const int b = t >> 5;         // capsule
    const int a = blockIdx.x;

    // ---- load x[a]: 1152 floats = 288 f4 -> fp16 LDS ----
    if (t < 288) {
        f4 v = reinterpret_cast<const f4*>(xg + (size_t)a * (INC * IND))[t];
        h4v hv;
        hv[0] = (_Float16)v[0]; hv[1] = (_Float16)v[1];
        hv[2] = (_Float16)v[2]; hv[3] = (_Float16)v[3];
        *reinterpret_cast<h4v*>(x_h + t * 4) = hv;
    }
    __syncthreads();

    // hat[b][c][half*8+0..7]: 9 NAMED h8 (36 VGPRs; r18 lesson: fit the 128 clamp)
#define DECLH(K) h8 hc##K;
    R9(DECLH)
#define DECLS(D) float s##D;
    R8(DECLS)
#define ZEROS(D) s##D = 0.f;

    // one d of one c: W row dot x row (4 fdot2), stash fp16, accumulate s_d
#define HD1(DG) { \
    float ac; \
    if constexpr (sizeof(WT) == 2) { \
        H8 w; w.v = *reinterpret_cast<const h8*>(wr + (DG) * 128 + cg * 8); \
        ac = fdot2(w.p[0], xv.p[0], 0.f); \
        ac = fdot2(w.p[1], xv.p[1], ac); \
        ac = fdot2(w.p[2], xv.p[2], ac); \
        ac = fdot2(w.p[3], xv.p[3], ac); \
    } else { \
        const float* wf = reinterpret_cast<const float*>(wr) + (DG) * IND; \
        f4 w0 = *reinterpret_cast<const f4*>(wf); \
        f4 w1 = *reinterpret_cast<const f4*>(wf + 4); \
        ac = (float)xv.e[0] * w0[0]; \
        ac = fmaf((float)xv.e[1], w0[1], ac); \
        ac = fmaf((float)xv.e[2], w0[2], ac); \
        ac = fmaf((float)xv.e[3], w0[3], ac); \
        ac = fmaf((float)xv.e[4], w1[0], ac); \
        ac = fmaf((float)xv.e[5], w1[1], ac); \
        ac = fmaf((float)xv.e[6], w1[2], ac); \
        ac = fmaf((float)xv.e[7], w1[3], ac); \
    } \
    tV.e[DG] = (_Float16)ac; s##DG += ac; }

#define HSTEP(K) { \
    const int c = cg + 16 * (K); \
    H8 xv; xv.v = *reinterpret_cast<const h8*>(x_h + c * IND); \
    const WT* wr; \
    if constexpr (sizeof(WT) == 2) \
        wr = Wg + ((size_t)(b * 9 + (K)) * 2048 + half * 1024); \
    else \
        wr = Wg + ((size_t)(b * INC + c) * DC + half * 8) * IND; \
    H8 tV; \
    HD1(0) HD1(1) HD1(2) HD1(3) HD1(4) HD1(5) HD1(6) HD1(7) \
    hc##K = tV.v; }

    R8(ZEROS)
    R9(HSTEP)

    // butterfly over cg (16-lane groups share (b,half)): full 144-c sums
#define BF1(D) s##D += __shfl_xor(s##D, 1, 16);
#define BF2(D) s##D += __shfl_xor(s##D, 2, 16);
#define BF4(D) s##D += __shfl_xor(s##D, 4, 16);
#define BF8(D) s##D += __shfl_xor(s##D, 8, 16);
#define SCL(D) s##D *= (1.0f / 32.0f);
    R8(BF1) R8(BF2) R8(BF4) R8(BF8)
    R8(SCL)  // softmax(0) uniform coefficients

#define SUMSQH (s0*s0+s1*s1+s2*s2+s3*s3+s4*s4+s5*s5+s6*s6+s7*s7)

    h8 oV;
#define PACKO { \
    float n2 = SUMSQH; \
    n2 += __shfl_xor(n2, 16, 32);  /* add other d-half */ \
    float ff = n2 / ((1.0f + n2) * sqrtf(n2 + 1e-7f)); \
    H8 pk; \
    pk.e[0]=(_Float16)(s0*ff); pk.e[1]=(_Float16)(s1*ff); \
    pk.e[2]=(_Float16)(s2*ff); pk.e[3]=(_Float16)(s3*ff); \
    pk.e[4]=(_Float16)(s4*ff); pk.e[5]=(_Float16)(s5*ff); \
    pk.e[6]=(_Float16)(s6*ff); pk.e[7]=(_Float16)(s7*ff); \
    oV = pk.v; }
    PACKO

#define DECLG(K) float lgr##K = 0.f;
    R9(DECLG)

    // B-pass: half-dot over own 8 d's + one cross-half shuffle = full 16-d dot
#define BSTEP(K) { \
    H8 hv; hv.v = hc##K; \
    H8 ov; ov.v = oV; \
    float dt = fdot2(hv.p[0], ov.p[0], 0.f); \
    dt = fdot2(hv.p[1], ov.p[1], dt); \
    dt = fdot2(hv.p[2], ov.p[2], dt); \
    dt = fdot2(hv.p[3], ov.p[3], dt); \
    dt += __shfl_xor(dt, 16, 32); \
    lgr##K += dt; \
    lg[b * LG_S + cg + 16 * (K)] = (_Float16)lgr##K; }

    // S-pass: fp32 fma over own 9 c's x 8 d's; cg-butterfly later
#define SSTEP(K) { \
    float cf = (float)lg[b * LG_S + cg + 16 * (K)]; \
    H8 hv; hv.v = hc##K; \
    s0 = fmaf(cf, (float)hv.e[0], s0); s1 = fmaf(cf, (float)hv.e[1], s1); \
    s2 = fmaf(cf, (float)hv.e[2], s2); s3 = fmaf(cf, (float)hv.e[3], s3); \
    s4 = fmaf(cf, (float)hv.e[4], s4); s5 = fmaf(cf, (float)hv.e[5], s5); \
    s6 = fmaf(cf, (float)hv.e[6], s6); s7 = fmaf(cf, (float)hv.e[7], s7); }

    for (int it = 0; it < 2; ++it) {
        R9(BSTEP)
        __syncthreads();

        // softmax over 32 capsules: 2 threads per c, 16 bb's each, named regs
        if (t < 2 * INC) {
            const int c = t >> 1;
            const int rb = (t & 1) * 16;
#define SMR(I) float v##I = (float)lg[(rb + I) * LG_S + c];
            R16(SMR)
            float m = fmaxf(v0, v1);
#define SMM(I) m = fmaxf(m, v##I);
            SMM(2) SMM(3) SMM(4) SMM(5) SMM(6) SMM(7) SMM(8) SMM(9)
            SMM(10) SMM(11) SMM(12) SMM(13) SMM(14) SMM(15)
            m = fmaxf(m, __shfl_xor(m, 1));
            float S = 0.f;
#define SME(I) v##I = __expf(v##I - m); S += v##I;
            R16(SME)
            S += __shfl_xor(S, 1);
            float inv = 1.0f / S;
#define SMW(I) lg[(rb + I) * LG_S + c] = (_Float16)(v##I * inv);
            R16(SMW)
        }
        __syncthreads();

        R8(ZEROS)
        R9(SSTEP)
        R8(BF1) R8(BF2) R8(BF4) R8(BF8)

        if (it == 0) {
            PACKO
            __syncthreads();  // S-reads of lg done before next B-pass writes
        } else {
            float n2 = SUMSQH;
            n2 += __shfl_xor(n2, 16, 32);
            float ff = n2 / ((1.0f + n2) * sqrtf(n2 + 1e-7f));
            if (cg < 8) {
                float r = s0;
                if (cg == 1) r = s1; if (cg == 2) r = s2; if (cg == 3) r = s3;
                if (cg == 4) r = s4; if (cg == 5) r = s5; if (cg == 6) r = s6;
                if (cg == 7) r = s7;
                // out[a][b][half*8+cg], coalesced within each 16-lane group
                out[(size_t)a * (NC * DC) + b * DC + half * 8 + cg] = r * ff;
            }
        }
    }
}

extern "C" void kernel_launch(void* const* d_in, const int* in_sizes, int n_in,
                              void* d_out, int out_size, void* d_ws, size_t ws_size,
                              hipStream_t stream) {
    const float* x = (const float*)d_in[0];
    const float* W = (const float*)d_in[1];
    float* out = (float*)d_out;

    const size_t WH_BYTES = (size_t)NC * INC * DC * IND * 2;  // 1179648

    if (ws_size >= WH_BYTES) {
        _Float16* Wh = (_Float16*)d_ws;
        hipLaunchKernelGGL(convw_kernel, dim3(288), dim3(256), 0, stream, W, Wh);
        hipLaunchKernelGGL(caps_kernel<_Float16>, dim3(512), dim3(NT), 0,
                           stream, x, Wh, out);
    } else {
        hipLaunchKernelGGL(caps_kernel<float>, dim3(512), dim3(NT), 0,
                           stream, x, W, out);
    }
}

// Round 20
// 50.025 us; speedup vs baseline: 1.4909x; 1.4909x over previous
//
#include <hip/hip_runtime.h>

#define NC 32     // num_capsule
#define DC 16     // dim_capsule
#define INC 144   // input capsules
#define IND 8     // input dim
#define NT 512    // threads: (b 0..31) x (cg 0..15)
#define LG_S 152  // halves per b row of logits

// LDS (halves): hatL[32][144][8] | pad | hatH[32][144][8] | lg[32][152] (x overlaps lg)
// hat rows are THREAD-PRIVATE (owner-only access) -> no barriers, no conflicts:
// 16-lane group reads consecutive 16B rows = ideal LDS pattern.
#define HATL_OFF 0
#define HATH_OFF (NC * INC * IND + 8)          // 36872; 16B-aligned
#define LG_OFF (HATH_OFF + NC * INC * IND)     // 73736; 16B-aligned
#define SMEM_HALVES (LG_OFF + NC * LG_S)       // 78600
#define SMEM_BYTES (SMEM_HALVES * 2)           // 157200 <= 163840

typedef _Float16 h2 __attribute__((ext_vector_type(2)));
typedef _Float16 h4v __attribute__((ext_vector_type(4)));
typedef _Float16 h8 __attribute__((ext_vector_type(8)));
typedef float f4 __attribute__((ext_vector_type(4)));

union H8 { h8 v; h2 p[4]; _Float16 e[8]; };

#if __has_builtin(__builtin_amdgcn_fdot2)
__device__ __forceinline__ float fdot2(h2 a, h2 b, float c) {
    return __builtin_amdgcn_fdot2(a, b, c, false);
}
#else
__device__ __forceinline__ float fdot2(h2 a, h2 b, float c) {
    return c + (float)a[0] * (float)b[0] + (float)a[1] * (float)b[1];
}
#endif

// Convert+TRANSPOSE W: fp32 [b][c][d][i] -> fp16 h8-slots [(b*9+k)*16+d][cg],
// c = cg + 16k. 73728 h8 slots -> grid 288 x 256.
__global__ void convw_kernel(const float* __restrict__ W, _Float16* __restrict__ Wh) {
    int i = blockIdx.x * 256 + threadIdx.x;          // h8 slot 0..73727
    int cg = i & 15, d = (i >> 4) & 15, bk = i >> 8; // bk = b*9+k, 0..287
    int k = bk % 9, b = bk / 9;
    const float* s = W + (((size_t)b * INC + cg + 16 * k) * DC + d) * IND;
    f4 v0 = *reinterpret_cast<const f4*>(s);
    f4 v1 = *reinterpret_cast<const f4*>(s + 4);
    H8 o;
    o.e[0] = (_Float16)v0[0]; o.e[1] = (_Float16)v0[1];
    o.e[2] = (_Float16)v0[2]; o.e[3] = (_Float16)v0[3];
    o.e[4] = (_Float16)v1[0]; o.e[5] = (_Float16)v1[1];
    o.e[6] = (_Float16)v1[2]; o.e[7] = (_Float16)v1[3];
    *reinterpret_cast<h8*>(Wh + (size_t)i * 8) = o.v;
}

#define R9(M)  M(0) M(1) M(2) M(3) M(4) M(5) M(6) M(7) M(8)
#define R16(M) M(0) M(1) M(2) M(3) M(4) M(5) M(6) M(7) M(8) M(9) M(10) M(11) M(12) M(13) M(14) M(15)

template <typename WT>
__global__ __launch_bounds__(NT)
__attribute__((amdgpu_waves_per_eu(2, 4)))  // demand ~60 regs: fits ANY budget, spill impossible
void caps_kernel(const float* __restrict__ xg, const WT* __restrict__ Wg,
                 float* __restrict__ out) {
    extern __shared__ __align__(16) _Float16 sm[];
    _Float16* lg = sm + LG_OFF;
    _Float16* x_h = lg;  // overlap: x only live during phase H (barrier before lg use)

    const int t = threadIdx.x;
    const int b = t >> 4;    // capsule
    const int cg = t & 15;   // c-group: owns c = cg + 16k, all 16 d
    const int a = blockIdx.x;

    // ---- load x[a]: 1152 floats = 288 f4 -> fp16 LDS ----
    if (t < 288) {
        f4 v = reinterpret_cast<const f4*>(xg + (size_t)a * (INC * IND))[t];
        h4v hv;
        hv[0] = (_Float16)v[0]; hv[1] = (_Float16)v[1];
        hv[2] = (_Float16)v[2]; hv[3] = (_Float16)v[3];
        *reinterpret_cast<h4v*>(x_h + t * 4) = hv;
    }
    __syncthreads();

#define DECLS(D) float s##D;
    R16(DECLS)
#define ZEROS(D) s##D = 0.f;

    // one d of one c: W row dot x row (4 fdot2), stash fp16, accumulate s_d
#define HD1(T, E, DG) { \
    float ac; \
    if constexpr (sizeof(WT) == 2) { \
        H8 w; w.v = *reinterpret_cast<const h8*>(wr + (DG) * 128 + cg * 8); \
        ac = fdot2(w.p[0], xv.p[0], 0.f); \
        ac = fdot2(w.p[1], xv.p[1], ac); \
        ac = fdot2(w.p[2], xv.p[2], ac); \
        ac = fdot2(w.p[3], xv.p[3], ac); \
    } else { \
        const float* wf = reinterpret_cast<const float*>(wr) + (DG) * IND; \
        f4 w0 = *reinterpret_cast<const f4*>(wf); \
        f4 w1 = *reinterpret_cast<const f4*>(wf + 4); \
        ac = (float)xv.e[0] * w0[0]; \
        ac = fmaf((float)xv.e[1], w0[1], ac); \
        ac = fmaf((float)xv.e[2], w0[2], ac); \
        ac = fmaf((float)xv.e[3], w0[3], ac); \
        ac = fmaf((float)xv.e[4], w1[0], ac); \
        ac = fmaf((float)xv.e[5], w1[1], ac); \
        ac = fmaf((float)xv.e[6], w1[2], ac); \
        ac = fmaf((float)xv.e[7], w1[3], ac); \
    } \
    T.e[E] = (_Float16)ac; s##DG += ac; }

    // Phase H: hat[b][c][:] for own 9 c's -> LDS rows (b128, owner-private)
#define HSTEP(K) { \
    const int c = cg + 16 * (K); \
    H8 xv; xv.v = *reinterpret_cast<const h8*>(x_h + c * IND); \
    const WT* wr; \
    if constexpr (sizeof(WT) == 2) wr = Wg + ((size_t)(b * 9 + (K)) * 2048); \
    else wr = Wg + ((size_t)(b * INC + c) * (DC * IND)); \
    H8 tL, tH; \
    HD1(tL,0,0) HD1(tL,1,1) HD1(tL,2,2) HD1(tL,3,3) \
    HD1(tL,4,4) HD1(tL,5,5) HD1(tL,6,6) HD1(tL,7,7) \
    HD1(tH,0,8) HD1(tH,1,9) HD1(tH,2,10) HD1(tH,3,11) \
    HD1(tH,4,12) HD1(tH,5,13) HD1(tH,6,14) HD1(tH,7,15) \
    *reinterpret_cast<h8*>(sm + HATL_OFF + (size_t)(b * INC + c) * 8) = tL.v; \
    *reinterpret_cast<h8*>(sm + HATH_OFF + (size_t)(b * INC + c) * 8) = tH.v; }

    R16(ZEROS)
    R9(HSTEP)
    __syncthreads();  // x_h reads done everywhere before B-pass writes lg (overlap)

    // 16-lane fp32 butterfly allreduce over the b-group (lanes share b)
#define BF1(D) s##D += __shfl_xor(s##D, 1, 16);
#define BF2(D) s##D += __shfl_xor(s##D, 2, 16);
#define BF4(D) s##D += __shfl_xor(s##D, 4, 16);
#define BF8(D) s##D += __shfl_xor(s##D, 8, 16);
#define SCL(D) s##D *= (1.0f / 32.0f);
    R16(BF1) R16(BF2) R16(BF4) R16(BF8)
    R16(SCL)  // softmax(0) uniform coefficients

#define SUMSQ (s0*s0+s1*s1+s2*s2+s3*s3+s4*s4+s5*s5+s6*s6+s7*s7+ \
               s8*s8+s9*s9+s10*s10+s11*s11+s12*s12+s13*s13+s14*s14+s15*s15)

    h8 oLv, oHv;
#define PACKO { \
    float n2 = SUMSQ; \
    float ff = n2 / ((1.0f + n2) * sqrtf(n2 + 1e-7f)); \
    H8 pl, ph; \
    pl.e[0]=(_Float16)(s0*ff);  pl.e[1]=(_Float16)(s1*ff); \
    pl.e[2]=(_Float16)(s2*ff);  pl.e[3]=(_Float16)(s3*ff); \
    pl.e[4]=(_Float16)(s4*ff);  pl.e[5]=(_Float16)(s5*ff); \
    pl.e[6]=(_Float16)(s6*ff);  pl.e[7]=(_Float16)(s7*ff); \
    ph.e[0]=(_Float16)(s8*ff);  ph.e[1]=(_Float16)(s9*ff); \
    ph.e[2]=(_Float16)(s10*ff); ph.e[3]=(_Float16)(s11*ff); \
    ph.e[4]=(_Float16)(s12*ff); ph.e[5]=(_Float16)(s13*ff); \
    ph.e[6]=(_Float16)(s14*ff); ph.e[7]=(_Float16)(s15*ff); \
    oLv = pl.v; oHv = ph.v; }
    PACKO

#define DECLG(K) float lgr##K = 0.f;
    R9(DECLG)

    // B-pass: logit[b][c] += o . hat[b][c][:] -- own LDS rows, thread-local
#define BSTEP(K) { \
    const int c = cg + 16 * (K); \
    H8 hl, hh; \
    hl.v = *reinterpret_cast<const h8*>(sm + HATL_OFF + (size_t)(b * INC + c) * 8); \
    hh.v = *reinterpret_cast<const h8*>(sm + HATH_OFF + (size_t)(b * INC + c) * 8); \
    H8 ol, oh; ol.v = oLv; oh.v = oHv; \
    float dt = fdot2(hl.p[0], ol.p[0], 0.f); \
    dt = fdot2(hl.p[1], ol.p[1], dt); \
    dt = fdot2(hl.p[2], ol.p[2], dt); \
    dt = fdot2(hl.p[3], ol.p[3], dt); \
    dt = fdot2(hh.p[0], oh.p[0], dt); \
    dt = fdot2(hh.p[1], oh.p[1], dt); \
    dt = fdot2(hh.p[2], oh.p[2], dt); \
    dt = fdot2(hh.p[3], oh.p[3], dt); \
    lgr##K += dt; \
    lg[b * LG_S + c] = (_Float16)lgr##K; }

    // S-pass: s_d += cc[b][c] * hat[c][d] over own 9 c's; butterfly later
#define SSTEP(K) { \
    const int c = cg + 16 * (K); \
    float cf = (float)lg[b * LG_S + c]; \
    H8 hl, hh; \
    hl.v = *reinterpret_cast<const h8*>(sm + HATL_OFF + (size_t)(b * INC + c) * 8); \
    hh.v = *reinterpret_cast<const h8*>(sm + HATH_OFF + (size_t)(b * INC + c) * 8); \
    s0  = fmaf(cf, (float)hl.e[0], s0);  s1  = fmaf(cf, (float)hl.e[1], s1); \
    s2  = fmaf(cf, (float)hl.e[2], s2);  s3  = fmaf(cf, (float)hl.e[3], s3); \
    s4  = fmaf(cf, (float)hl.e[4], s4);  s5  = fmaf(cf, (float)hl.e[5], s5); \
    s6  = fmaf(cf, (float)hl.e[6], s6);  s7  = fmaf(cf, (float)hl.e[7], s7); \
    s8  = fmaf(cf, (float)hh.e[0], s8);  s9  = fmaf(cf, (float)hh.e[1], s9); \
    s10 = fmaf(cf, (float)hh.e[2], s10); s11 = fmaf(cf, (float)hh.e[3], s11); \
    s12 = fmaf(cf, (float)hh.e[4], s12); s13 = fmaf(cf, (float)hh.e[5], s13); \
    s14 = fmaf(cf, (float)hh.e[6], s14); s15 = fmaf(cf, (float)hh.e[7], s15); }

    for (int it = 0; it < 2; ++it) {
        R9(BSTEP)
        __syncthreads();

        // softmax over 32 capsules: 2 threads per c, 16 bb's each, named regs
        if (t < 2 * INC) {
            const int c = t >> 1;
            const int rb = (t & 1) * 16;
#define SMR(I) float v##I = (float)lg[(rb + I) * LG_S + c];
            R16(SMR)
            float m = fmaxf(v0, v1);
#define SMM(I) m = fmaxf(m, v##I);
            SMM(2) SMM(3) SMM(4) SMM(5) SMM(6) SMM(7) SMM(8) SMM(9)
            SMM(10) SMM(11) SMM(12) SMM(13) SMM(14) SMM(15)
            m = fmaxf(m, __shfl_xor(m, 1));
            float S = 0.f;
#define SME(I) v##I = __expf(v##I - m); S += v##I;
            R16(SME)
            S += __shfl_xor(S, 1);
            float inv = 1.0f / S;
#define SMW(I) lg[(rb + I) * LG_S + c] = (_Float16)(v##I * inv);
            R16(SMW)
        }
        __syncthreads();

        R16(ZEROS)
        R9(SSTEP)
        R16(BF1) R16(BF2) R16(BF4) R16(BF8)

        if (it == 0) {
            PACKO
            __syncthreads();  // S-reads of lg done before next B-pass writes
        } else {
            float n2 = SUMSQ;
            float ff = n2 / ((1.0f + n2) * sqrtf(n2 + 1e-7f));
            float r = s0;
            if (cg == 1) r = s1;   if (cg == 2) r = s2;   if (cg == 3) r = s3;
            if (cg == 4) r = s4;   if (cg == 5) r = s5;   if (cg == 6) r = s6;
            if (cg == 7) r = s7;   if (cg == 8) r = s8;   if (cg == 9) r = s9;
            if (cg == 10) r = s10; if (cg == 11) r = s11; if (cg == 12) r = s12;
            if (cg == 13) r = s13; if (cg == 14) r = s14; if (cg == 15) r = s15;
            out[(size_t)a * (NC * DC) + t] = r * ff;  // out[a][b][d=cg], coalesced
        }
    }
}

extern "C" void kernel_launch(void* const* d_in, const int* in_sizes, int n_in,
                              void* d_out, int out_size, void* d_ws, size_t ws_size,
                              hipStream_t stream) {
    const float* x = (const float*)d_in[0];
    const float* W = (const float*)d_in[1];
    float* out = (float*)d_out;

    const size_t WH_BYTES = (size_t)NC * INC * DC * IND * 2;  // 1179648

    if (ws_size >= WH_BYTES) {
        _Float16* Wh = (_Float16*)d_ws;
        hipLaunchKernelGGL(convw_kernel, dim3(288), dim3(256), 0, stream, W, Wh);
        hipFuncSetAttribute(reinterpret_cast<const void*>(&caps_kernel<_Float16>),
                            hipFuncAttributeMaxDynamicSharedMemorySize, SMEM_BYTES);
        hipLaunchKernelGGL(caps_kernel<_Float16>, dim3(512), dim3(NT), SMEM_BYTES,
                           stream, x, Wh, out);
    } else {
        hipFuncSetAttribute(reinterpret_cast<const void*>(&caps_kernel<float>),
                            hipFuncAttributeMaxDynamicSharedMemorySize, SMEM_BYTES);
        hipLaunchKernelGGL(caps_kernel<float>, dim3(512), dim3(NT), SMEM_BYTES,
                           stream, x, W, out);
    }
}